// Round 1
// baseline (32422.638 us; speedup 1.0000x reference)
//
#include <hip/hip_runtime.h>
#include <cstdint>
#include <cstddef>

#define HH 512
#define DD 256
#define BB 64
#define SS 2048
#define G3 1536

// LDS layout for gru_scan (floats): Wl[48][516] | hl[8][516] | prt[384][21] | xil[8][52] | hhl[8][49]
#define SMEM_FLOATS (48*516 + 8*516 + 384*21 + 8*52 + 8*49)
#define SMEM_BYTES  (SMEM_FLOATS * 4)

// ---------------- Wh [512][1536] -> Wt [1536][512] ----------------
__global__ __launch_bounds__(256) void transpose_wh(const float* __restrict__ Wh,
                                                    float* __restrict__ Wt) {
    __shared__ float t[32][33];
    int bx = blockIdx.x % 48;            // g tile
    int by = blockIdx.x / 48;            // k tile
    int x = threadIdx.x & 31, y0 = threadIdx.x >> 5;
#pragma unroll
    for (int i = 0; i < 32; i += 8)
        t[y0 + i][x] = Wh[(size_t)(by * 32 + y0 + i) * G3 + bx * 32 + x];
    __syncthreads();
#pragma unroll
    for (int i = 0; i < 32; i += 8)
        Wt[(size_t)(bx * 32 + y0 + i) * HH + by * 32 + x] = t[x][y0 + i];
}

// ------------- fused embedding gather + xi GEMM: xi[m][g] = emb[tok(m)] @ Wi + bi -------------
// M = BB*SC rows (chunk-local), N = 1536, K = 256. Tiles 128x128xBK8, 8x8 per thread.
__global__ __launch_bounds__(256, 2) void xi_gemm(const int* __restrict__ tokens,
                                                  const float* __restrict__ emb,
                                                  const float* __restrict__ Wi,
                                                  const float* __restrict__ bi,
                                                  float* __restrict__ xi,
                                                  int chunk_start, int SC) {
    __shared__ float Al[8][132];
    __shared__ float Bl[8][132];
    __shared__ int   toks[128];
    const int tid = threadIdx.x;
    const int m0 = blockIdx.x * 128;
    const int n0 = blockIdx.y * 128;
    if (tid < 128) {
        int m = m0 + tid;
        int b = m / SC, s = m % SC;
        toks[tid] = tokens[b * SS + chunk_start + s];
    }
    float acc[8][8];
#pragma unroll
    for (int i = 0; i < 8; ++i)
#pragma unroll
        for (int j = 0; j < 8; ++j) acc[i][j] = 0.f;
    const int tm = tid & 15, tn = (tid >> 4) & 15;
    const int ma = tid & 127, kq = tid >> 7;
    const int bk = tid >> 5,  bn = tid & 31;
    __syncthreads();
    for (int k0 = 0; k0 < DD; k0 += 8) {
        float4 av = *(const float4*)(emb + (size_t)toks[ma] * DD + k0 + kq * 4);
        float4 bv = *(const float4*)(Wi + (size_t)(k0 + bk) * G3 + n0 + bn * 4);
        Al[kq*4+0][ma] = av.x; Al[kq*4+1][ma] = av.y;
        Al[kq*4+2][ma] = av.z; Al[kq*4+3][ma] = av.w;
        *(float4*)&Bl[bk][bn*4] = bv;
        __syncthreads();
#pragma unroll
        for (int k = 0; k < 8; ++k) {
            float a[8], bbv[8];
            *(float4*)&a[0]   = *(const float4*)&Al[k][tm*4];
            *(float4*)&a[4]   = *(const float4*)&Al[k][64 + tm*4];
            *(float4*)&bbv[0] = *(const float4*)&Bl[k][tn*4];
            *(float4*)&bbv[4] = *(const float4*)&Bl[k][64 + tn*4];
#pragma unroll
            for (int i = 0; i < 8; ++i)
#pragma unroll
                for (int j = 0; j < 8; ++j) acc[i][j] += a[i] * bbv[j];
        }
        __syncthreads();
    }
    float4 b0v = *(const float4*)(bi + n0 + tn*4);
    float4 b1v = *(const float4*)(bi + n0 + 64 + tn*4);
#pragma unroll
    for (int i = 0; i < 8; ++i) {
        int m = m0 + (i < 4 ? tm*4 + i : 64 + tm*4 + (i - 4));
        float* orow = xi + (size_t)m * G3 + n0;
        float4 o0 = make_float4(acc[i][0]+b0v.x, acc[i][1]+b0v.y, acc[i][2]+b0v.z, acc[i][3]+b0v.w);
        float4 o1 = make_float4(acc[i][4]+b1v.x, acc[i][5]+b1v.y, acc[i][6]+b1v.z, acc[i][7]+b1v.w);
        *(float4*)(orow + tn*4) = o0;
        *(float4*)(orow + 64 + tn*4) = o1;
    }
}

// ------------- GRU scan: 8 batch-groups x 32 j-slice wgs, Wh slice pinned in LDS -------------
__global__ __launch_bounds__(256, 1) void gru_scan(const float* __restrict__ xi,
                                                   const float* __restrict__ Wt,
                                                   const float* __restrict__ bhn,
                                                   float* __restrict__ hbuf,
                                                   unsigned int* __restrict__ cnt,
                                                   float* __restrict__ out,
                                                   int chunk_start, int SC) {
    extern __shared__ float smf[];
    float* Wl  = smf;                    // [48][516]
    float* hl  = Wl  + 48*516;           // [8][516]
    float* prt = hl  + 8*516;            // [384][21]
    float* xil = prt + 384*21;           // [8][52]
    float* hhl = xil + 8*52;             // [8][49]

    const int tid = threadIdx.x;
    const int grp = blockIdx.x & 7;      // batch group (XCD-aligned under %8 round-robin)
    const int mem = blockIdx.x >> 3;     // j-slice 0..31
    const int j0 = mem * 16;
    const int b0 = grp * 8;

    // Load Wh slice: 48 gate-cols (c = gate*16+jj) x 512 k, coalesced from Wt[g][k].
    for (int i = tid; i < 48 * 128; i += 256) {
        int c = i >> 7, kq = (i & 127) << 2;
        int g = (c >> 4) * HH + j0 + (c & 15);
        *(float4*)&Wl[c * 516 + kq] = *(const float4*)(Wt + (size_t)g * HH + kq);
    }
    float bhn_r = 0.f;
    if (tid < 128) bhn_r = bhn[j0 + (tid & 15)];

    const int tg = tid >> 4, ks = tid & 15;   // 16 g-tiles x 16 k-slices
    unsigned int target = 0;

    for (int s = 0; s < SC; ++s) {
        const int t = chunk_start + s;
        const float* hsrc = hbuf + (size_t)(t & 1) * (BB * HH);
        float*       hdst = hbuf + (size_t)((t + 1) & 1) * (BB * HH);
        // stage h(t) for our 8 batches: 1024 float4
#pragma unroll
        for (int i = 0; i < 4; ++i) {
            int idx = tid + i * 256;
            int b = idx >> 7, kq = (idx & 127) << 2;
            *(float4*)&hl[b * 516 + kq] = *(const float4*)(hsrc + (b0 + b) * HH + kq);
        }
        // stage xi(t) for (8 b x 3 gates x 16 j): 96 float4
        if (tid < 96) {
            int b = tid / 12, q = tid % 12;
            int gate = q >> 2, f = (q & 3) << 2;
            *(float4*)&xil[b * 52 + gate * 16 + f] =
                *(const float4*)(xi + ((size_t)(b0 + b) * SC + s) * G3 + gate * HH + j0 + f);
        }
        __syncthreads();
        // MAC: thread = (tg, ks): 8 batches x 3 g-cols (c = 3*tg+gi) x 32 k (ks*4 + m*64)
        {
            float acc[3][8];
#pragma unroll
            for (int gi = 0; gi < 3; ++gi)
#pragma unroll
                for (int b = 0; b < 8; ++b) acc[gi][b] = 0.f;
#pragma unroll
            for (int m = 0; m < 8; ++m) {
                int k = (ks << 2) + (m << 6);
                float4 w0 = *(const float4*)&Wl[(3*tg+0)*516 + k];
                float4 w1 = *(const float4*)&Wl[(3*tg+1)*516 + k];
                float4 w2 = *(const float4*)&Wl[(3*tg+2)*516 + k];
#pragma unroll
                for (int b = 0; b < 8; ++b) {
                    float4 hv = *(const float4*)&hl[b*516 + k];
                    acc[0][b] += w0.x*hv.x + w0.y*hv.y + w0.z*hv.z + w0.w*hv.w;
                    acc[1][b] += w1.x*hv.x + w1.y*hv.y + w1.z*hv.z + w1.w*hv.w;
                    acc[2][b] += w2.x*hv.x + w2.y*hv.y + w2.z*hv.z + w2.w*hv.w;
                }
            }
#pragma unroll
            for (int gi = 0; gi < 3; ++gi)
#pragma unroll
                for (int b = 0; b < 8; ++b)
                    prt[(tg + (((gi << 3) + b) << 4)) * 21 + ks] = acc[gi][b];
        }
        __syncthreads();
        // reduce 16 k-slices per output
        for (int o = tid; o < 384; o += 256) {
            float ssum = 0.f;
#pragma unroll
            for (int q = 0; q < 16; ++q) ssum += prt[o * 21 + q];
            int tgo = o & 15, q2 = o >> 4, gi = q2 >> 3, b = q2 & 7;
            hhl[b * 49 + 3 * tgo + gi] = ssum;
        }
        __syncthreads();
        // gates + state update for (8 b x 16 j)
        if (tid < 128) {
            int b = tid >> 4, jj = tid & 15;
            float hhR = hhl[b*49 + jj];
            float hhZ = hhl[b*49 + 16 + jj];
            float hhN = hhl[b*49 + 32 + jj];
            float xiR = xil[b*52 + jj];
            float xiZ = xil[b*52 + 16 + jj];
            float xiN = xil[b*52 + 32 + jj];
            float hold = hl[b*516 + j0 + jj];
            float r = 1.f / (1.f + expf(-(xiR + hhR)));
            float z = 1.f / (1.f + expf(-(xiZ + hhZ)));
            float n = tanhf(xiN + r * (hhN + bhn_r));
            float hnew = (1.f - z) * n + z * hold;
            hdst[(b0 + b) * HH + j0 + jj] = hnew;
            out[((size_t)(b0 + b) * SS + t) * HH + j0 + jj] = hnew;
        }
        __syncthreads();   // drains vmcnt: all wg stores in L2 before fence
        target += 32;
        if (tid == 0) {
            __threadfence();                       // release: cross-XCD writeback
            atomicAdd(&cnt[grp << 6], 1u);
            while (__hip_atomic_load(&cnt[grp << 6], __ATOMIC_RELAXED,
                                     __HIP_MEMORY_SCOPE_AGENT) < target)
                __builtin_amdgcn_s_sleep(2);
            __threadfence();                       // acquire: invalidate stale lines
        }
        __syncthreads();
    }
}

extern "C" void kernel_launch(void* const* d_in, const int* in_sizes, int n_in,
                              void* d_out, int out_size, void* d_ws, size_t ws_size,
                              hipStream_t stream) {
    const int*   tokens = (const int*)d_in[0];
    const float* emb    = (const float*)d_in[1];
    const float* Wi     = (const float*)d_in[2];
    const float* bi     = (const float*)d_in[3];
    const float* Wh     = (const float*)d_in[4];
    const float* bhn    = (const float*)d_in[5];
    float* out = (float*)d_out;

    char* ws = (char*)d_ws;
    float*        Wt   = (float*)ws;                                  // 3 MB
    float*        hbuf = (float*)(ws + (3 << 20));                    // 2 x 128 KB ping-pong
    unsigned int* cnt  = (unsigned int*)(ws + (3 << 20) + BB*HH*2*4); // 8 x 256B counters
    float*        xi   = (float*)(ws + (4 << 20));                    // chunk xi buffer

    // pick largest chunk length SC (divides 2048) whose xi buffer fits the workspace
    size_t avail = ws_size > ((size_t)4 << 20) ? ws_size - ((size_t)4 << 20) : 0;
    int SC = 64;
    const int cands[5] = {2048, 1024, 512, 256, 128};
    for (int i = 0; i < 5; ++i) {
        if ((size_t)cands[i] * BB * G3 * 4 <= avail) { SC = cands[i]; break; }
    }

    hipFuncSetAttribute((const void*)gru_scan,
                        hipFuncAttributeMaxDynamicSharedMemorySize, SMEM_BYTES);

    hipMemsetAsync(hbuf, 0, BB * HH * 2 * 4, stream);
    transpose_wh<<<768, 256, 0, stream>>>(Wh, Wt);

    int nch = SS / SC;
    for (int c = 0; c < nch; ++c) {
        int cs = c * SC;
        xi_gemm<<<dim3((BB * SC) / 128, 12), 256, 0, stream>>>(tokens, emb, Wi, bi, xi, cs, SC);
        hipMemsetAsync(cnt, 0, 8 * 64 * 4, stream);
        void* args[] = {(void*)&xi, (void*)&Wt, (void*)&bhn, (void*)&hbuf,
                        (void*)&cnt, (void*)&out, (void*)&cs, (void*)&SC};
        hipLaunchCooperativeKernel((void*)gru_scan, dim3(256), dim3(256), args,
                                   SMEM_BYTES, stream);
    }
}

// Round 2
// 18530.695 us; speedup vs baseline: 1.7497x; 1.7497x over previous
//
#include <hip/hip_runtime.h>
#include <cstdint>
#include <cstddef>

#define HH 512
#define DD 256
#define BB 64
#define SS 2048
#define G3 1536

typedef float f32x4 __attribute__((ext_vector_type(4)));

// LDS layout for gru_scan (floats): Wl[48][516] | hl[8][516] | prt[384][21] | xil[8][52] | hhl[8][49]
#define SMEM_FLOATS (48*516 + 8*516 + 384*21 + 8*52 + 8*49)
#define SMEM_BYTES  (SMEM_FLOATS * 4)

// ---------------- Wh [512][1536] -> Wt [1536][512] ----------------
__global__ __launch_bounds__(256) void transpose_wh(const float* __restrict__ Wh,
                                                    float* __restrict__ Wt) {
    __shared__ float t[32][33];
    int bx = blockIdx.x % 48;            // g tile
    int by = blockIdx.x / 48;            // k tile
    int x = threadIdx.x & 31, y0 = threadIdx.x >> 5;
#pragma unroll
    for (int i = 0; i < 32; i += 8)
        t[y0 + i][x] = Wh[(size_t)(by * 32 + y0 + i) * G3 + bx * 32 + x];
    __syncthreads();
#pragma unroll
    for (int i = 0; i < 32; i += 8)
        Wt[(size_t)(bx * 32 + y0 + i) * HH + by * 32 + x] = t[x][y0 + i];
}

// ------------- fused embedding gather + xi GEMM: xi[m][g] = emb[tok(m)] @ Wi + bi -------------
__global__ __launch_bounds__(256, 2) void xi_gemm(const int* __restrict__ tokens,
                                                  const float* __restrict__ emb,
                                                  const float* __restrict__ Wi,
                                                  const float* __restrict__ bi,
                                                  float* __restrict__ xi,
                                                  int chunk_start, int SC) {
    __shared__ float Al[8][132];
    __shared__ float Bl[8][132];
    __shared__ int   toks[128];
    const int tid = threadIdx.x;
    const int m0 = blockIdx.x * 128;
    const int n0 = blockIdx.y * 128;
    if (tid < 128) {
        int m = m0 + tid;
        int b = m / SC, s = m % SC;
        toks[tid] = tokens[b * SS + chunk_start + s];
    }
    float acc[8][8];
#pragma unroll
    for (int i = 0; i < 8; ++i)
#pragma unroll
        for (int j = 0; j < 8; ++j) acc[i][j] = 0.f;
    const int tm = tid & 15, tn = (tid >> 4) & 15;
    const int ma = tid & 127, kq = tid >> 7;
    const int bk = tid >> 5,  bn = tid & 31;
    __syncthreads();
    for (int k0 = 0; k0 < DD; k0 += 8) {
        float4 av = *(const float4*)(emb + (size_t)toks[ma] * DD + k0 + kq * 4);
        float4 bv = *(const float4*)(Wi + (size_t)(k0 + bk) * G3 + n0 + bn * 4);
        Al[kq*4+0][ma] = av.x; Al[kq*4+1][ma] = av.y;
        Al[kq*4+2][ma] = av.z; Al[kq*4+3][ma] = av.w;
        *(float4*)&Bl[bk][bn*4] = bv;
        __syncthreads();
#pragma unroll
        for (int k = 0; k < 8; ++k) {
            float a[8], bbv[8];
            *(float4*)&a[0]   = *(const float4*)&Al[k][tm*4];
            *(float4*)&a[4]   = *(const float4*)&Al[k][64 + tm*4];
            *(float4*)&bbv[0] = *(const float4*)&Bl[k][tn*4];
            *(float4*)&bbv[4] = *(const float4*)&Bl[k][64 + tn*4];
#pragma unroll
            for (int i = 0; i < 8; ++i)
#pragma unroll
                for (int j = 0; j < 8; ++j) acc[i][j] += a[i] * bbv[j];
        }
        __syncthreads();
    }
    float4 b0v = *(const float4*)(bi + n0 + tn*4);
    float4 b1v = *(const float4*)(bi + n0 + 64 + tn*4);
#pragma unroll
    for (int i = 0; i < 8; ++i) {
        int m = m0 + (i < 4 ? tm*4 + i : 64 + tm*4 + (i - 4));
        float* orow = xi + (size_t)m * G3 + n0;
        float4 o0 = make_float4(acc[i][0]+b0v.x, acc[i][1]+b0v.y, acc[i][2]+b0v.z, acc[i][3]+b0v.w);
        float4 o1 = make_float4(acc[i][4]+b1v.x, acc[i][5]+b1v.y, acc[i][6]+b1v.z, acc[i][7]+b1v.w);
        *(float4*)(orow + tn*4) = o0;
        *(float4*)(orow + 64 + tn*4) = o1;
    }
}

// ------------- GRU scan: 8 batch-groups x 32 j-slice wgs, Wh slice pinned in LDS -------------
// Cross-wg h exchange is done entirely with sc0 sc1 (coherence-point) accesses:
// no __threadfence -> no buffer_wbl2 / buffer_inv L2 flushes per step.
__global__ __launch_bounds__(256, 1) void gru_scan(const float* __restrict__ xi,
                                                   const float* __restrict__ Wt,
                                                   const float* __restrict__ bhn,
                                                   float* __restrict__ hbuf,
                                                   unsigned int* __restrict__ cnt,
                                                   float* __restrict__ out,
                                                   int chunk_start, int SC) {
    extern __shared__ float smf[];
    float* Wl  = smf;                    // [48][516]
    float* hl  = Wl  + 48*516;           // [8][516]
    float* prt = hl  + 8*516;            // [384][21]
    float* xil = prt + 384*21;           // [8][52]
    float* hhl = xil + 8*52;             // [8][49]

    const int tid = threadIdx.x;
    const int grp = blockIdx.x & 7;      // batch group
    const int mem = blockIdx.x >> 3;     // j-slice 0..31
    const int j0 = mem * 16;
    const int b0 = grp * 8;

    // Load Wh slice: 48 gate-cols (c = gate*16+jj) x 512 k, coalesced from Wt[g][k].
    for (int i = tid; i < 48 * 128; i += 256) {
        int c = i >> 7, kq = (i & 127) << 2;
        int g = (c >> 4) * HH + j0 + (c & 15);
        *(float4*)&Wl[c * 516 + kq] = *(const float4*)(Wt + (size_t)g * HH + kq);
    }
    float bhn_r = 0.f;
    if (tid < 128) bhn_r = bhn[j0 + (tid & 15)];

    const int tg = tid >> 4, ks = tid & 15;   // 16 g-tiles x 16 k-slices
    const int bh = tid >> 7;                  // h-staging base batch (0/1)
    const int kq = (tid & 127) << 2;          // h-staging k quad
    unsigned int* cptr = &cnt[grp << 6];
    unsigned int target = 0;

    for (int s = 0; s < SC; ++s) {
        const int t = chunk_start + s;
        const float* hsrc = hbuf + (size_t)(t & 1) * (BB * HH);
        float*       hdst = hbuf + (size_t)((t + 1) & 1) * (BB * HH);

        // stage h(t) for our 8 batches: 4 x dwordx4 per thread, sc0 sc1 (L3-coherent)
        {
            const float* p0 = hsrc + (size_t)(b0 + bh) * HH + kq;
            const float* p1 = p0 + 2 * HH;
            const float* p2 = p0 + 4 * HH;
            const float* p3 = p0 + 6 * HH;
            f32x4 h0v, h1v, h2v, h3v;
            asm volatile(
                "global_load_dwordx4 %0, %4, off sc0 sc1\n\t"
                "global_load_dwordx4 %1, %5, off sc0 sc1\n\t"
                "global_load_dwordx4 %2, %6, off sc0 sc1\n\t"
                "global_load_dwordx4 %3, %7, off sc0 sc1\n\t"
                "s_waitcnt vmcnt(0)"
                : "=&v"(h0v), "=&v"(h1v), "=&v"(h2v), "=&v"(h3v)
                : "v"(p0), "v"(p1), "v"(p2), "v"(p3)
                : "memory");
            *(f32x4*)&hl[(bh + 0) * 516 + kq] = h0v;
            *(f32x4*)&hl[(bh + 2) * 516 + kq] = h1v;
            *(f32x4*)&hl[(bh + 4) * 516 + kq] = h2v;
            *(f32x4*)&hl[(bh + 6) * 516 + kq] = h3v;
        }
        // stage xi(t) for (8 b x 3 gates x 16 j): 96 float4 (normal cached loads)
        if (tid < 96) {
            int b = tid / 12, q = tid % 12;
            int gate = q >> 2, f = (q & 3) << 2;
            *(float4*)&xil[b * 52 + gate * 16 + f] =
                *(const float4*)(xi + ((size_t)(b0 + b) * SC + s) * G3 + gate * HH + j0 + f);
        }
        __syncthreads();
        // MAC: thread = (tg, ks): 8 batches x 3 g-cols x 32 k
        {
            float acc[3][8];
#pragma unroll
            for (int gi = 0; gi < 3; ++gi)
#pragma unroll
                for (int b = 0; b < 8; ++b) acc[gi][b] = 0.f;
#pragma unroll
            for (int m = 0; m < 8; ++m) {
                int k = (ks << 2) + (m << 6);
                float4 w0 = *(const float4*)&Wl[(3*tg+0)*516 + k];
                float4 w1 = *(const float4*)&Wl[(3*tg+1)*516 + k];
                float4 w2 = *(const float4*)&Wl[(3*tg+2)*516 + k];
#pragma unroll
                for (int b = 0; b < 8; ++b) {
                    float4 hv = *(const float4*)&hl[b*516 + k];
                    acc[0][b] += w0.x*hv.x + w0.y*hv.y + w0.z*hv.z + w0.w*hv.w;
                    acc[1][b] += w1.x*hv.x + w1.y*hv.y + w1.z*hv.z + w1.w*hv.w;
                    acc[2][b] += w2.x*hv.x + w2.y*hv.y + w2.z*hv.z + w2.w*hv.w;
                }
            }
#pragma unroll
            for (int gi = 0; gi < 3; ++gi)
#pragma unroll
                for (int b = 0; b < 8; ++b)
                    prt[(tg + (((gi << 3) + b) << 4)) * 21 + ks] = acc[gi][b];
        }
        __syncthreads();
        // reduce 16 k-slices per output
        for (int o = tid; o < 384; o += 256) {
            float ssum = 0.f;
#pragma unroll
            for (int q = 0; q < 16; ++q) ssum += prt[o * 21 + q];
            int tgo = o & 15, q2 = o >> 4, gi = q2 >> 3, b = q2 & 7;
            hhl[b * 49 + 3 * tgo + gi] = ssum;
        }
        __syncthreads();
        // gates + state update for (8 b x 16 j)
        if (tid < 128) {
            int b = tid >> 4, jj = tid & 15;
            float hhR = hhl[b*49 + jj];
            float hhZ = hhl[b*49 + 16 + jj];
            float hhN = hhl[b*49 + 32 + jj];
            float xiR = xil[b*52 + jj];
            float xiZ = xil[b*52 + 16 + jj];
            float xiN = xil[b*52 + 32 + jj];
            float hold = hl[b*516 + j0 + jj];
            float r = 1.f / (1.f + expf(-(xiR + hhR)));
            float z = 1.f / (1.f + expf(-(xiZ + hhZ)));
            float n = tanhf(xiN + r * (hhN + bhn_r));
            float hnew = (1.f - z) * n + z * hold;
            float* hp = hdst + (size_t)(b0 + b) * HH + j0 + jj;
            asm volatile("global_store_dword %0, %1, off sc0 sc1"
                         :: "v"(hp), "v"(hnew) : "memory");
            out[((size_t)(b0 + b) * SS + t) * HH + j0 + jj] = hnew;
        }
        // release: sc1 store retirement == visible at coherence point (no buffer_wbl2)
        asm volatile("s_waitcnt vmcnt(0)" ::: "memory");
        __syncthreads();
        target += 32;
        if (tid == 0) {
            __hip_atomic_fetch_add(cptr, 1u, __ATOMIC_RELAXED, __HIP_MEMORY_SCOPE_AGENT);
            unsigned int v;
            do {
                asm volatile(
                    "global_load_dword %0, %1, off sc0 sc1\n\t"
                    "s_waitcnt vmcnt(0)"
                    : "=v"(v) : "v"(cptr) : "memory");
                if (v >= target) break;
                asm volatile("s_sleep 1");
            } while (true);
        }
        __syncthreads();
    }
}

extern "C" void kernel_launch(void* const* d_in, const int* in_sizes, int n_in,
                              void* d_out, int out_size, void* d_ws, size_t ws_size,
                              hipStream_t stream) {
    const int*   tokens = (const int*)d_in[0];
    const float* emb    = (const float*)d_in[1];
    const float* Wi     = (const float*)d_in[2];
    const float* bi     = (const float*)d_in[3];
    const float* Wh     = (const float*)d_in[4];
    const float* bhn    = (const float*)d_in[5];
    float* out = (float*)d_out;

    char* ws = (char*)d_ws;
    float*        Wt   = (float*)ws;                                  // 3 MB
    float*        hbuf = (float*)(ws + (3 << 20));                    // 2 x 128 KB ping-pong
    unsigned int* cnt  = (unsigned int*)(ws + (3 << 20) + BB*HH*2*4); // 8 x 256B counters
    float*        xi   = (float*)(ws + (4 << 20));                    // chunk xi buffer

    size_t avail = ws_size > ((size_t)4 << 20) ? ws_size - ((size_t)4 << 20) : 0;
    int SC = 64;
    const int cands[5] = {2048, 1024, 512, 256, 128};
    for (int i = 0; i < 5; ++i) {
        if ((size_t)cands[i] * BB * G3 * 4 <= avail) { SC = cands[i]; break; }
    }

    hipFuncSetAttribute((const void*)gru_scan,
                        hipFuncAttributeMaxDynamicSharedMemorySize, SMEM_BYTES);

    hipMemsetAsync(hbuf, 0, BB * HH * 2 * 4, stream);
    transpose_wh<<<768, 256, 0, stream>>>(Wh, Wt);

    int nch = SS / SC;
    for (int c = 0; c < nch; ++c) {
        int cs = c * SC;
        xi_gemm<<<dim3((BB * SC) / 128, 12), 256, 0, stream>>>(tokens, emb, Wi, bi, xi, cs, SC);
        hipMemsetAsync(cnt, 0, 8 * 64 * 4, stream);
        void* args[] = {(void*)&xi, (void*)&Wt, (void*)&bhn, (void*)&hbuf,
                        (void*)&cnt, (void*)&out, (void*)&cs, (void*)&SC};
        hipLaunchCooperativeKernel((void*)gru_scan, dim3(256), dim3(256), args,
                                   SMEM_BYTES, stream);
    }
}